// Round 7
// baseline (281.385 us; speedup 1.0000x reference)
//
#include <hip/hip_runtime.h>

typedef __bf16 bf16x8 __attribute__((ext_vector_type(8)));
typedef float f32x4 __attribute__((ext_vector_type(4)));
typedef unsigned int uint32;
typedef unsigned short u16;

#define NST 21
#define SCL 0.3606737602222409f  // 0.25*log2(e); softmax = exp2(s), shift-free

union U4B { uint4 u; bf16x8 b; };

__device__ __forceinline__ uint32 pkbf(float a, float b) {  // RTNE pack
  uint32 ua = __float_as_uint(a), ub = __float_as_uint(b);
  ua += 0x7fffu + ((ua >> 16) & 1u);
  ub += 0x7fffu + ((ub >> 16) & 1u);
  return (ua >> 16) | (ub & 0xffff0000u);
}
__device__ __forceinline__ u16 bf1(float a) {
  uint32 u = __float_as_uint(a);
  u += 0x7fffu + ((u >> 16) & 1u);
  return (u16)(u >> 16);
}
// 1-instr truncating pack: lo16 = lo.hi16, hi16 = hi.hi16 (CK idiom)
__device__ __forceinline__ uint32 pkperm(float lo, float hi) {
  return __builtin_amdgcn_perm(__float_as_uint(hi), __float_as_uint(lo), 0x07060302u);
}

// =====================================================================
// prep (reordered: slow hetero blocks first so they aren't stragglers):
// bid 0..511   station projections (2 stations/block)
// bid 512..551 weight transposes -> bf16 WtAll (8 blocks per matrix)
// bid 552..4647 q/hx f32->bf16 cast
// =====================================================================
__global__ __launch_bounds__(256) void prep(
    const float* __restrict__ q, const float* __restrict__ hx,
    const float* __restrict__ W0, const float* __restrict__ W1,
    const float* __restrict__ W2, const float* __restrict__ W3,
    const float* __restrict__ W4, const float* __restrict__ Wqst,
    const float* __restrict__ Wks, const float* __restrict__ Wvs,
    u16* __restrict__ qhbf, u16* __restrict__ WtAll, u16* __restrict__ Qm,
    u16* __restrict__ Ks, u16* __restrict__ Vs) {
  int bid = blockIdx.x, tid = threadIdx.x;
  __shared__ float xq2[2][128], xh2[2][128];
  if (bid < 512) {
    int t2 = bid;                   // 0..511
    int sub = tid >> 7, col = tid & 127;
    int hh = col >> 4, k = col & 15;
    int bs2 = t2 * 2 + sub;         // 0..1023
    int b2 = bs2 >> 5, s = bs2 & 31;
    if (s < NST) {
      xq2[sub][col] = q[(size_t)(b2 * 1024 + s) * 128 + col];
      xh2[sub][col] = hx[(size_t)(b2 * 1024 + s) * 128 + col];
    }
    __syncthreads();
    if (s < NST) {
      const float* Wq = Wqst + hh * 2048 + k;
      const float* Wk = Wks + hh * 2048 + k;
      const float* Wv = Wvs + hh * 2048 + k;
      float dq = 0.f, dk_ = 0.f, dv = 0.f;
#pragma unroll 8
      for (int d = 0; d < 128; ++d) {
        float xq = xq2[sub][d], xh = xh2[sub][d];
        dq = fmaf(xq, Wq[d * 16], dq);
        dk_ = fmaf(xh, Wk[d * 16], dk_);
        dv = fmaf(xh, Wv[d * 16], dv);
      }
      Qm[(((size_t)hh * 32 + b2) * 1024 + s) * 16 + k] = bf1(dq * SCL);
      Ks[(((size_t)hh * 32 + b2) * 32 + s) * 16 + k] = bf1(dk_);
      Vs[(((size_t)hh * 32 + b2) * 16 + k) * 32 + s] = bf1(dv);
    } else {
      Ks[(((size_t)hh * 32 + b2) * 32 + s) * 16 + k] = 0;
      Vs[(((size_t)hh * 32 + b2) * 16 + k) * 32 + s] = 0;
    }
  } else if (bid < 552) {
    int wb = bid - 512;
    int w = wb >> 3, seg = wb & 7;
    const float* W = (w == 0) ? W0 : (w == 1) ? W1 : (w == 2) ? W2
                     : (w == 3) ? W3 : W4;
    u16* dst = WtAll + w * 16384;
#pragma unroll
    for (int it = 0; it < 8; ++it) {
      int i = seg * 2048 + it * 256 + tid;  // 0..16383
      int inner = i & 127, outer = i >> 7;
      float v;
      if (w < 4) {
        int h = outer >> 4, k = outer & 15;
        v = W[h * 2048 + inner * 16 + k];
      } else {
        v = W[inner * 128 + outer];
      }
      dst[outer * 128 + inner] = bf1(v);
    }
  } else {
    int i0 = (bid - 552) * 2048 + tid * 8;  // 8 floats per thread
    const float* src = (i0 < 4194304) ? (q + i0) : (hx + (i0 - 4194304));
    float4 a = *(const float4*)src;
    float4 b = *(const float4*)(src + 4);
    uint4 o;
    o.x = pkbf(a.x, a.y); o.y = pkbf(a.z, a.w);
    o.z = pkbf(b.x, b.y); o.w = pkbf(b.z, b.w);
    *((uint4*)qhbf + (i0 >> 3)) = o;
  }
}

// =====================================================================
// MFMA GEMM body: out(64 rows x 128) = A_bf16(64x128) @ Wt^T; A pre-cast.
// Wl stride 138 (was 136): kills the 8-way bank conflict on B reads.
// mode 0: Qm bf16 [h][b][n][16] scaled, skip n<21 (prep owns those rows)
// mode 1: Qts bf16, scaled, all rows       mode 2: Kc bf16 [h][b][n][16]
// mode 3: Vc bf16 TRANSPOSED [h][b][k16][n1024]   mode 4: f32 out [m][128]
// =====================================================================
__device__ __forceinline__ void mm_body(const u16* __restrict__ A,
                                        const u16* __restrict__ WtG,
                                        int m0, int mode, void* outp) {
  __shared__ u16 Wl[128 * 138];
  int tid = threadIdx.x;
#pragma unroll
  for (int r = 0; r < 8; ++r) {
    int i = r * 256 + tid;
    int e = i >> 4, j = i & 15;
    *(uint4*)&Wl[e * 138 + j * 8] = *(const uint4*)(WtG + e * 128 + j * 8);
  }
  __syncthreads();
  int wave = tid >> 6, lane = tid & 63;
  int quad = lane >> 4, l15 = lane & 15;
  int mrow = m0 + wave * 16 + l15;

  f32x4 c[8];
#pragma unroll
  for (int nt = 0; nt < 8; ++nt)
#pragma unroll
    for (int r = 0; r < 4; ++r) c[nt][r] = 0.f;

#pragma unroll
  for (int dk = 0; dk < 4; ++dk) {
    U4B af;
    af.u = *(const uint4*)(A + (size_t)mrow * 128 + dk * 32 + quad * 8);
#pragma unroll
    for (int nt = 0; nt < 8; ++nt) {
      U4B bg;
      bg.u = *(const uint4*)&Wl[(nt * 16 + l15) * 138 + dk * 32 + quad * 8];
      c[nt] = __builtin_amdgcn_mfma_f32_16x16x32_bf16(af.b, bg.b, c[nt], 0, 0, 0);
    }
  }
  int gbase = m0 + wave * 16 + quad * 4;
  int bb = gbase >> 10, n0 = gbase & 1023;
  if (mode == 4) {
#pragma unroll
    for (int nt = 0; nt < 8; ++nt)
#pragma unroll
      for (int r = 0; r < 4; ++r)
        ((float*)outp)[(size_t)(gbase + r) * 128 + nt * 16 + l15] = c[nt][r];
  } else if (mode == 3) {
#pragma unroll
    for (int nt = 0; nt < 8; ++nt) {
      uint2 w2 = make_uint2(pkbf(c[nt][0], c[nt][1]), pkbf(c[nt][2], c[nt][3]));
      *(uint2*)((u16*)outp + (((size_t)nt * 32 + bb) * 16 + l15) * 1024 + n0) = w2;
    }
  } else {
    float scale = (mode <= 1) ? SCL : 1.0f;
#pragma unroll
    for (int nt = 0; nt < 8; ++nt)
#pragma unroll
      for (int r = 0; r < 4; ++r) {
        int n = n0 + r;
        if (mode == 0 && n < NST) continue;
        ((u16*)outp)[(((size_t)nt * 32 + bb) * 1024 + n) * 16 + l15] =
            bf1(c[nt][r] * scale);
      }
  }
}

__global__ __launch_bounds__(256) void proj4(
    const u16* __restrict__ qbf, const u16* __restrict__ hbf,
    const u16* __restrict__ WtAll, u16* __restrict__ Qm,
    u16* __restrict__ Qts, u16* __restrict__ Kc, u16* __restrict__ Vc) {
  int mode = blockIdx.x >> 9, mb = blockIdx.x & 511;
  const u16* A = (mode < 2) ? qbf : hbf;
  void* outp = (mode == 0) ? (void*)Qm : (mode == 1) ? (void*)Qts
               : (mode == 2) ? (void*)Kc : (void*)Vc;
  mm_body(A, WtAll + mode * 16384, mb * 64, mode, outp);
}

__global__ __launch_bounds__(256) void outproj(
    const u16* __restrict__ heads, const u16* __restrict__ WtAll,
    float* __restrict__ out) {
  mm_body(heads, WtAll + 4 * 16384, blockIdx.x * 64, 4, out);
}

// =====================================================================
// attn_main v2: layout-chained MFMA, zero LDS, zero barriers.
// Per wave: 16 queries (q = qw0+l15). 32-key steps with EVEN/ODD key
// interleave:
//   QK: A = K rows (even keys at l15), B = Q (k 16..31 zeroed)
//       -> C: lane holds scores for query l15, keys 2*(4*quad+r) (+1 odd)
//   pack perm(pe_r, po_r) -> exactly PV's B = P[key=quad*8+j][q=l15]
//   PV: A = V^T (Vc pre-transposed), B = P -> O^T: query stays l15.
// lsum: 8 VALU adds/step + 2 cross-quad shuffles at the end.
// Station pass: same chain once over Ks/Vs (keys>=21 masked).
// =====================================================================
__global__ __launch_bounds__(256) void attn_main(
    const u16* __restrict__ Qm, const u16* __restrict__ Qts,
    const u16* __restrict__ Kc, const u16* __restrict__ Vc,
    const u16* __restrict__ Ks, const u16* __restrict__ Vs,
    u16* __restrict__ heads) {
  int bx = blockIdx.x;
  int hb = bx & 255, qc = bx >> 8;
  int h = hb >> 5, b = hb & 31;
  int tid = threadIdx.x;
  int wave = tid >> 6, lane = tid & 63;
  int quad = lane >> 4, l15 = lane & 15;
  int q8 = (quad & 1) * 8;
  int xq = quad * 4;

  const u16* Qbase = Qm + (size_t)hb * 16384;
  const u16* Kbase = Kc + (size_t)hb * 16384;
  const u16* Vbase = Vc + (size_t)hb * 16384;
  const u16* QtsB = Qts + (size_t)hb * 16384;
  const u16* KsB = Ks + (size_t)hb * 512;
  const u16* VsB = Vs + (size_t)hb * 512;

  int qw0 = qc * 64 + wave * 16;

  U4B qf;
  qf.u = make_uint4(0u, 0u, 0u, 0u);
  if (lane < 32) qf.u = *(const uint4*)(Qbase + (size_t)(qw0 + l15) * 16 + q8);

  f32x4 zero4 = {0.f, 0.f, 0.f, 0.f};
  f32x4 o = zero4, o2 = zero4;
  float lsum = 0.f, ls2 = 0.f;

  // ---- step 0 (keys 0..31; zero keys<21 = stations) ----
  {
    U4B ae, ao, av;
    ae.u = *(const uint4*)(Kbase + (size_t)(2 * l15) * 16 + q8);
    ao.u = *(const uint4*)(Kbase + (size_t)(2 * l15 + 1) * 16 + q8);
    av.u = *(const uint4*)(Vbase + (size_t)l15 * 1024 + quad * 8);
    f32x4 ce = __builtin_amdgcn_mfma_f32_16x16x32_bf16(ae.b, qf.b, zero4, 0, 0, 0);
    f32x4 co = __builtin_amdgcn_mfma_f32_16x16x32_bf16(ao.b, qf.b, zero4, 0, 0, 0);
    float pe[4], po[4];
#pragma unroll
    for (int r = 0; r < 4; ++r) {
      pe[r] = (xq + r <= 10) ? 0.f : __builtin_amdgcn_exp2f(ce[r]);  // even key 2x<21
      po[r] = (xq + r <= 9) ? 0.f : __builtin_amdgcn_exp2f(co[r]);   // odd key 2x+1<21
    }
    lsum += ((pe[0] + po[0]) + (pe[1] + po[1])) + ((pe[2] + po[2]) + (pe[3] + po[3]));
    U4B pk;
    pk.u.x = pkperm(pe[0], po[0]); pk.u.y = pkperm(pe[1], po[1]);
    pk.u.z = pkperm(pe[2], po[2]); pk.u.w = pkperm(pe[3], po[3]);
    o = __builtin_amdgcn_mfma_f32_16x16x32_bf16(av.b, pk.b, o, 0, 0, 0);
  }
  // ---- steps 1..31 (clean) ----
#pragma unroll 2
  for (int s = 1; s < 32; ++s) {
    int j0 = s * 32;
    U4B ae, ao, av;
    ae.u = *(const uint4*)(Kbase + (size_t)(j0 + 2 * l15) * 16 + q8);
    ao.u = *(const uint4*)(Kbase + (size_t)(j0 + 2 * l15 + 1) * 16 + q8);
    av.u = *(const uint4*)(Vbase + (size_t)l15 * 1024 + j0 + quad * 8);
    f32x4 ce = __builtin_amdgcn_mfma_f32_16x16x32_bf16(ae.b, qf.b, zero4, 0, 0, 0);
    f32x4 co = __builtin_amdgcn_mfma_f32_16x16x32_bf16(ao.b, qf.b, zero4, 0, 0, 0);
    float pe[4], po[4];
#pragma unroll
    for (int r = 0; r < 4; ++r) {
      pe[r] = __builtin_amdgcn_exp2f(ce[r]);
      po[r] = __builtin_amdgcn_exp2f(co[r]);
    }
    lsum += ((pe[0] + po[0]) + (pe[1] + po[1])) + ((pe[2] + po[2]) + (pe[3] + po[3]));
    U4B pk;
    pk.u.x = pkperm(pe[0], po[0]); pk.u.y = pkperm(pe[1], po[1]);
    pk.u.z = pkperm(pe[2], po[2]); pk.u.w = pkperm(pe[3], po[3]);
    o = __builtin_amdgcn_mfma_f32_16x16x32_bf16(av.b, pk.b, o, 0, 0, 0);
  }

  // ---- station pass: Q = Q_ts, keys = K_s/V_s (slots >=21 masked) ----
  {
    U4B q2;
    q2.u = make_uint4(0u, 0u, 0u, 0u);
    if (lane < 32) q2.u = *(const uint4*)(QtsB + (size_t)(qw0 + l15) * 16 + q8);
    U4B ae, ao, av;
    ae.u = *(const uint4*)(KsB + (2 * l15) * 16 + q8);
    ao.u = *(const uint4*)(KsB + (2 * l15 + 1) * 16 + q8);
    av.u = *(const uint4*)(VsB + l15 * 32 + quad * 8);
    f32x4 ce = __builtin_amdgcn_mfma_f32_16x16x32_bf16(ae.b, q2.b, zero4, 0, 0, 0);
    f32x4 co = __builtin_amdgcn_mfma_f32_16x16x32_bf16(ao.b, q2.b, zero4, 0, 0, 0);
    float pe[4], po[4];
#pragma unroll
    for (int r = 0; r < 4; ++r) {
      pe[r] = (xq + r >= 11) ? 0.f : __builtin_amdgcn_exp2f(ce[r]);  // keep 2x<21
      po[r] = (xq + r >= 10) ? 0.f : __builtin_amdgcn_exp2f(co[r]);  // keep 2x+1<21
    }
    ls2 += ((pe[0] + po[0]) + (pe[1] + po[1])) + ((pe[2] + po[2]) + (pe[3] + po[3]));
    U4B pk;
    pk.u.x = pkperm(pe[0], po[0]); pk.u.y = pkperm(pe[1], po[1]);
    pk.u.z = pkperm(pe[2], po[2]); pk.u.w = pkperm(pe[3], po[3]);
    o2 = __builtin_amdgcn_mfma_f32_16x16x32_bf16(av.b, pk.b, o2, 0, 0, 0);
  }

  // ---- reduce + epilogue ----
  lsum += __shfl_xor(lsum, 16, 64);
  lsum += __shfl_xor(lsum, 32, 64);
  ls2 += __shfl_xor(ls2, 16, 64);
  ls2 += __shfl_xor(ls2, 32, 64);
  int n = qw0 + l15;
  float inv1 = __builtin_amdgcn_rcpf(lsum);
  float inv2 = __builtin_amdgcn_rcpf(ls2);
  float v0 = o[0] * inv1, v1 = o[1] * inv1, v2 = o[2] * inv1, v3 = o[3] * inv1;
  if (n >= NST) {
    v0 += o2[0] * inv2; v1 += o2[1] * inv2;
    v2 += o2[2] * inv2; v3 += o2[3] * inv2;
  }
  uint2 w2 = make_uint2(pkbf(v0, v1), pkbf(v2, v3));
  *(uint2*)(heads + ((size_t)b * 1024 + n) * 128 + h * 16 + quad * 4) = w2;
}

// =====================================================================
extern "C" void kernel_launch(void* const* d_in, const int* in_sizes, int n_in,
                              void* d_out, int out_size, void* d_ws,
                              size_t ws_size, hipStream_t stream) {
  (void)in_sizes; (void)n_in; (void)out_size; (void)ws_size;
  const float* q     = (const float*)d_in[0];
  const float* hx    = (const float*)d_in[1];
  const float* W_qts = (const float*)d_in[2];  // W_query_custom   -> Q_ts
  const float* W_qtt = (const float*)d_in[3];  // W_query_custom_1 -> Q_tt
  const float* W_kc  = (const float*)d_in[4];
  const float* W_vc  = (const float*)d_in[5];
  const float* W_qst = (const float*)d_in[6];  // W_query_charge_1 -> Q_st
  const float* W_ks  = (const float*)d_in[7];
  const float* W_vs  = (const float*)d_in[8];
  const float* W_out = (const float*)d_in[9];

  char* ws = (char*)d_ws;
  u16* qhbf  = (u16*)(ws + 0);          // q:8MB + hx:8MB (bf16 casts)
  u16* heads = (u16*)(ws + 0);          // reuse qbf slot (dead after proj4)
  u16* hbf   = (u16*)(ws + 8388608);
  u16* Qm    = (u16*)(ws + 16777216);   // [h][b][1024][16]
  u16* Qts   = (u16*)(ws + 25165824);
  u16* Kc    = (u16*)(ws + 33554432);   // [h][b][1024][16]
  u16* Vc    = (u16*)(ws + 41943040);   // [h][b][16][1024] (transposed)
  u16* Ks    = (u16*)(ws + 50331648);   // [h][b][32][16]
  u16* Vs    = (u16*)(ws + 50593792);   // [h][b][16][32]
  u16* WtAll = (u16*)(ws + 50855936);   // 5 x 128x128 bf16

  hipLaunchKernelGGL(prep, dim3(4648), dim3(256), 0, stream,
                     q, hx, W_qtt, W_qts, W_kc, W_vc, W_out, W_qst, W_ks, W_vs,
                     qhbf, WtAll, Qm, Ks, Vs);
  hipLaunchKernelGGL(proj4, dim3(2048), dim3(256), 0, stream,
                     qhbf, hbf, WtAll, Qm, Qts, Kc, Vc);
  hipLaunchKernelGGL(attn_main, dim3(4096), dim3(256), 0, stream,
                     Qm, Qts, Kc, Vc, Ks, Vs, heads);
  hipLaunchKernelGGL(outproj, dim3(512), dim3(256), 0, stream,
                     heads, WtAll, (float*)d_out);
}

// Round 8
// 196.642 us; speedup vs baseline: 1.4310x; 1.4310x over previous
//
#include <hip/hip_runtime.h>

typedef __bf16 bf16x8 __attribute__((ext_vector_type(8)));
typedef float f32x4 __attribute__((ext_vector_type(4)));
typedef unsigned int uint32;
typedef unsigned short u16;

#define NST 21
#define SCL 0.3606737602222409f  // 0.25*log2(e); softmax = exp2(s), shift-free

union U4B { uint4 u; bf16x8 b; };

__device__ __forceinline__ uint32 pkbf(float a, float b) {  // RTNE pack
  uint32 ua = __float_as_uint(a), ub = __float_as_uint(b);
  ua += 0x7fffu + ((ua >> 16) & 1u);
  ub += 0x7fffu + ((ub >> 16) & 1u);
  return (ua >> 16) | (ub & 0xffff0000u);
}
__device__ __forceinline__ u16 bf1(float a) {
  uint32 u = __float_as_uint(a);
  u += 0x7fffu + ((u >> 16) & 1u);
  return (u16)(u >> 16);
}
// 1-instr truncating pack: lo16 = lo.hi16, hi16 = hi.hi16 (CK idiom)
__device__ __forceinline__ uint32 pkperm(float lo, float hi) {
  return __builtin_amdgcn_perm(__float_as_uint(hi), __float_as_uint(lo), 0x07060302u);
}

// =====================================================================
// prep (slow hetero blocks first so they aren't stragglers):
// bid 0..511   station projections (2 stations/block)
// bid 512..551 weight transposes -> bf16 WtAll (8 blocks per matrix)
// bid 552..4647 q/hx f32->bf16 cast
// =====================================================================
__global__ __launch_bounds__(256) void prep(
    const float* __restrict__ q, const float* __restrict__ hx,
    const float* __restrict__ W0, const float* __restrict__ W1,
    const float* __restrict__ W2, const float* __restrict__ W3,
    const float* __restrict__ W4, const float* __restrict__ Wqst,
    const float* __restrict__ Wks, const float* __restrict__ Wvs,
    u16* __restrict__ qhbf, u16* __restrict__ WtAll, u16* __restrict__ Qm,
    u16* __restrict__ Ks, u16* __restrict__ Vs) {
  int bid = blockIdx.x, tid = threadIdx.x;
  __shared__ float xq2[2][128], xh2[2][128];
  if (bid < 512) {
    int t2 = bid;                   // 0..511
    int sub = tid >> 7, col = tid & 127;
    int hh = col >> 4, k = col & 15;
    int bs2 = t2 * 2 + sub;         // 0..1023
    int b2 = bs2 >> 5, s = bs2 & 31;
    if (s < NST) {
      xq2[sub][col] = q[(size_t)(b2 * 1024 + s) * 128 + col];
      xh2[sub][col] = hx[(size_t)(b2 * 1024 + s) * 128 + col];
    }
    __syncthreads();
    if (s < NST) {
      const float* Wq = Wqst + hh * 2048 + k;
      const float* Wk = Wks + hh * 2048 + k;
      const float* Wv = Wvs + hh * 2048 + k;
      float dq = 0.f, dk_ = 0.f, dv = 0.f;
#pragma unroll 8
      for (int d = 0; d < 128; ++d) {
        float xq = xq2[sub][d], xh = xh2[sub][d];
        dq = fmaf(xq, Wq[d * 16], dq);
        dk_ = fmaf(xh, Wk[d * 16], dk_);
        dv = fmaf(xh, Wv[d * 16], dv);
      }
      Qm[(((size_t)hh * 32 + b2) * 1024 + s) * 16 + k] = bf1(dq * SCL);
      Ks[(((size_t)hh * 32 + b2) * 32 + s) * 16 + k] = bf1(dk_);
      Vs[(((size_t)hh * 32 + b2) * 16 + k) * 32 + s] = bf1(dv);
    } else {
      Ks[(((size_t)hh * 32 + b2) * 32 + s) * 16 + k] = 0;
      Vs[(((size_t)hh * 32 + b2) * 16 + k) * 32 + s] = 0;
    }
  } else if (bid < 552) {
    int wb = bid - 512;
    int w = wb >> 3, seg = wb & 7;
    const float* W = (w == 0) ? W0 : (w == 1) ? W1 : (w == 2) ? W2
                     : (w == 3) ? W3 : W4;
    u16* dst = WtAll + w * 16384;
#pragma unroll
    for (int it = 0; it < 8; ++it) {
      int i = seg * 2048 + it * 256 + tid;  // 0..16383
      int inner = i & 127, outer = i >> 7;
      float v;
      if (w < 4) {
        int h = outer >> 4, k = outer & 15;
        v = W[h * 2048 + inner * 16 + k];
      } else {
        v = W[inner * 128 + outer];
      }
      dst[outer * 128 + inner] = bf1(v);
    }
  } else {
    int i0 = (bid - 552) * 2048 + tid * 8;  // 8 floats per thread
    const float* src = (i0 < 4194304) ? (q + i0) : (hx + (i0 - 4194304));
    float4 a = *(const float4*)src;
    float4 b = *(const float4*)(src + 4);
    uint4 o;
    o.x = pkbf(a.x, a.y); o.y = pkbf(a.z, a.w);
    o.z = pkbf(b.x, b.y); o.w = pkbf(b.z, b.w);
    *((uint4*)qhbf + (i0 >> 3)) = o;
  }
}

// =====================================================================
// MFMA GEMM body: out(64 rows x 128) = A_bf16(64x128) @ Wt^T; A pre-cast.
// Wl stride 138: conflict-free B reads.
// mode 0: Qm bf16 [h][b][n][16] scaled, skip n<21 (prep owns those rows)
// mode 1: Qts bf16, scaled, all rows       mode 2: Kc bf16 [h][b][n][16]
// mode 3: Vc bf16 TRANSPOSED [h][b][k16][n1024]   mode 4: f32 out [m][128]
// =====================================================================
__device__ __forceinline__ void mm_body(const u16* __restrict__ A,
                                        const u16* __restrict__ WtG,
                                        int m0, int mode, void* outp) {
  __shared__ u16 Wl[128 * 138];
  int tid = threadIdx.x;
#pragma unroll
  for (int r = 0; r < 8; ++r) {
    int i = r * 256 + tid;
    int e = i >> 4, j = i & 15;
    *(uint4*)&Wl[e * 138 + j * 8] = *(const uint4*)(WtG + e * 128 + j * 8);
  }
  __syncthreads();
  int wave = tid >> 6, lane = tid & 63;
  int quad = lane >> 4, l15 = lane & 15;
  int mrow = m0 + wave * 16 + l15;

  f32x4 c[8];
#pragma unroll
  for (int nt = 0; nt < 8; ++nt)
#pragma unroll
    for (int r = 0; r < 4; ++r) c[nt][r] = 0.f;

#pragma unroll
  for (int dk = 0; dk < 4; ++dk) {
    U4B af;
    af.u = *(const uint4*)(A + (size_t)mrow * 128 + dk * 32 + quad * 8);
#pragma unroll
    for (int nt = 0; nt < 8; ++nt) {
      U4B bg;
      bg.u = *(const uint4*)&Wl[(nt * 16 + l15) * 138 + dk * 32 + quad * 8];
      c[nt] = __builtin_amdgcn_mfma_f32_16x16x32_bf16(af.b, bg.b, c[nt], 0, 0, 0);
    }
  }
  int gbase = m0 + wave * 16 + quad * 4;
  int bb = gbase >> 10, n0 = gbase & 1023;
  if (mode == 4) {
#pragma unroll
    for (int nt = 0; nt < 8; ++nt)
#pragma unroll
      for (int r = 0; r < 4; ++r)
        ((float*)outp)[(size_t)(gbase + r) * 128 + nt * 16 + l15] = c[nt][r];
  } else if (mode == 3) {
#pragma unroll
    for (int nt = 0; nt < 8; ++nt) {
      uint2 w2 = make_uint2(pkbf(c[nt][0], c[nt][1]), pkbf(c[nt][2], c[nt][3]));
      *(uint2*)((u16*)outp + (((size_t)nt * 32 + bb) * 16 + l15) * 1024 + n0) = w2;
    }
  } else {
    float scale = (mode <= 1) ? SCL : 1.0f;
#pragma unroll
    for (int nt = 0; nt < 8; ++nt)
#pragma unroll
      for (int r = 0; r < 4; ++r) {
        int n = n0 + r;
        if (mode == 0 && n < NST) continue;
        ((u16*)outp)[(((size_t)nt * 32 + bb) * 1024 + n) * 16 + l15] =
            bf1(c[nt][r] * scale);
      }
  }
}

__global__ __launch_bounds__(256) void proj4(
    const u16* __restrict__ qbf, const u16* __restrict__ hbf,
    const u16* __restrict__ WtAll, u16* __restrict__ Qm,
    u16* __restrict__ Qts, u16* __restrict__ Kc, u16* __restrict__ Vc) {
  int mode = blockIdx.x >> 9, mb = blockIdx.x & 511;
  const u16* A = (mode < 2) ? qbf : hbf;
  void* outp = (mode == 0) ? (void*)Qm : (mode == 1) ? (void*)Qts
               : (mode == 2) ? (void*)Kc : (void*)Vc;
  mm_body(A, WtAll + mode * 16384, mb * 64, mode, outp);
}

__global__ __launch_bounds__(256) void outproj(
    const u16* __restrict__ heads, const u16* __restrict__ WtAll,
    float* __restrict__ out) {
  mm_body(heads, WtAll + 4 * 16384, blockIdx.x * 64, 4, out);
}

// =====================================================================
// attn_main v3 (hybrid): LDS-staged K/V tiles (shared by 4 waves) +
// layout-chained even/odd MFMA (no Pt LDS, no ones-MFMA).
// Per wave: 32 queries (2 fragments of 16, q = l15). Per 32-key step:
//   ae/ao = K rows even/odd (A-frag), qf = Q (k16..31 zeroed, B-frag)
//   QK C: lane = scores[key 2*(quad*4+r)(+1)][q=l15]
//   perm-pack (pe,po) pairs -> exactly PV's B = P[key][q]
//   PV: A = V^T slice -> O^T accumulates with q=l15 (no redistribution).
// lsum in VALU + cross-quad shuffles. Station pass: same chain once,
// keys >= 21 masked, read direct from global (L2-hot).
// grid 2048 = 256 (h,b) x 8 q-chunks of 128.
// =====================================================================
__global__ __launch_bounds__(256) void attn_main(
    const u16* __restrict__ Qm, const u16* __restrict__ Qts,
    const u16* __restrict__ Kc, const u16* __restrict__ Vc,
    const u16* __restrict__ Ks, const u16* __restrict__ Vs,
    u16* __restrict__ heads) {
  int bx = blockIdx.x;
  int hb = bx & 255, qc = bx >> 8;   // qc 0..7
  int h = hb >> 5, b = hb & 31;
  int tid = threadIdx.x;
  int wave = tid >> 6, lane = tid & 63;
  int quad = lane >> 4, l15 = lane & 15;
  int eo8 = (quad & 1) * 8;          // k-halves of Q/K rows
  int xq = quad * 4;                 // even-key base index / d base

  __shared__ u16 Kl[128 * 26];       // [key][26]: 52B rows, 13-bank step
  __shared__ u16 Vl[16 * 140];       // [d][140]: keys along row

  const u16* Qbase = Qm + (size_t)hb * 16384;
  const u16* QtsB = Qts + (size_t)hb * 16384;
  const u16* Kbase = Kc + (size_t)hb * 16384;
  const u16* Vbase = Vc + (size_t)hb * 16384;
  const u16* KsB = Ks + (size_t)hb * 512;
  const u16* VsB = Vs + (size_t)hb * 512;

  int qw0 = qc * 128 + wave * 32;    // 32 queries for this wave

  U4B qf0, qf1;
  qf0.u = make_uint4(0u, 0u, 0u, 0u);
  qf1.u = make_uint4(0u, 0u, 0u, 0u);
  if (lane < 32) {
    qf0.u = *(const uint4*)(Qbase + (size_t)(qw0 + l15) * 16 + eo8);
    qf1.u = *(const uint4*)(Qbase + (size_t)(qw0 + 16 + l15) * 16 + eo8);
  }

  f32x4 zero4 = {0.f, 0.f, 0.f, 0.f};
  f32x4 o0 = zero4, o1 = zero4;
  float ls0 = 0.f, ls1 = 0.f;

#pragma unroll 1
  for (int kb = 0; kb < 8; ++kb) {
    int j0 = kb * 128;
    __syncthreads();
    {
      int key = tid >> 1, half = tid & 1;
      *(uint4*)&Kl[key * 26 + half * 8] =
          *(const uint4*)(Kbase + (size_t)(j0 + key) * 16 + half * 8);
      int d = tid >> 4, kg = tid & 15;
      *(uint4*)&Vl[d * 140 + kg * 8] =
          *(const uint4*)(Vbase + (size_t)d * 1024 + j0 + kg * 8);
    }
    __syncthreads();
#pragma unroll 1
    for (int kt = 0; kt < 4; ++kt) {
      int key0 = kt * 32;
      U4B ae, ao, av;
      ae.u = *(const uint4*)&Kl[(key0 + 2 * l15) * 26 + eo8];
      ao.u = *(const uint4*)&Kl[(key0 + 2 * l15 + 1) * 26 + eo8];
      av.u = *(const uint4*)&Vl[l15 * 140 + key0 + quad * 8];
      f32x4 ce0 = __builtin_amdgcn_mfma_f32_16x16x32_bf16(ae.b, qf0.b, zero4, 0, 0, 0);
      f32x4 co0 = __builtin_amdgcn_mfma_f32_16x16x32_bf16(ao.b, qf0.b, zero4, 0, 0, 0);
      f32x4 ce1 = __builtin_amdgcn_mfma_f32_16x16x32_bf16(ae.b, qf1.b, zero4, 0, 0, 0);
      f32x4 co1 = __builtin_amdgcn_mfma_f32_16x16x32_bf16(ao.b, qf1.b, zero4, 0, 0, 0);
      bool masked = (kb == 0) && (kt == 0);
      float pe0[4], po0[4], pe1[4], po1[4];
#pragma unroll
      for (int r = 0; r < 4; ++r) {
        pe0[r] = __builtin_amdgcn_exp2f(ce0[r]);
        po0[r] = __builtin_amdgcn_exp2f(co0[r]);
        pe1[r] = __builtin_amdgcn_exp2f(ce1[r]);
        po1[r] = __builtin_amdgcn_exp2f(co1[r]);
        if (masked) {  // even key 2(xq+r) < 21, odd key 2(xq+r)+1 < 21
          bool me = (xq + r <= 10), mo = (xq + r <= 9);
          pe0[r] = me ? 0.f : pe0[r];
          po0[r] = mo ? 0.f : po0[r];
          pe1[r] = me ? 0.f : pe1[r];
          po1[r] = mo ? 0.f : po1[r];
        }
      }
      ls0 += ((pe0[0] + po0[0]) + (pe0[1] + po0[1])) +
             ((pe0[2] + po0[2]) + (pe0[3] + po0[3]));
      ls1 += ((pe1[0] + po1[0]) + (pe1[1] + po1[1])) +
             ((pe1[2] + po1[2]) + (pe1[3] + po1[3]));
      U4B pk0, pk1;
      pk0.u.x = pkperm(pe0[0], po0[0]); pk0.u.y = pkperm(pe0[1], po0[1]);
      pk0.u.z = pkperm(pe0[2], po0[2]); pk0.u.w = pkperm(pe0[3], po0[3]);
      pk1.u.x = pkperm(pe1[0], po1[0]); pk1.u.y = pkperm(pe1[1], po1[1]);
      pk1.u.z = pkperm(pe1[2], po1[2]); pk1.u.w = pkperm(pe1[3], po1[3]);
      o0 = __builtin_amdgcn_mfma_f32_16x16x32_bf16(av.b, pk0.b, o0, 0, 0, 0);
      o1 = __builtin_amdgcn_mfma_f32_16x16x32_bf16(av.b, pk1.b, o1, 0, 0, 0);
    }
  }

  // ---- station pass: Q = Q_ts, keys = K_s/V_s (slots >= 21 masked) ----
  f32x4 s0 = zero4, s1 = zero4;
  float t0 = 0.f, t1 = 0.f;
  {
    U4B q20, q21;
    q20.u = make_uint4(0u, 0u, 0u, 0u);
    q21.u = make_uint4(0u, 0u, 0u, 0u);
    if (lane < 32) {
      q20.u = *(const uint4*)(QtsB + (size_t)(qw0 + l15) * 16 + eo8);
      q21.u = *(const uint4*)(QtsB + (size_t)(qw0 + 16 + l15) * 16 + eo8);
    }
    U4B ae, ao, av;
    ae.u = *(const uint4*)(KsB + (2 * l15) * 16 + eo8);
    ao.u = *(const uint4*)(KsB + (2 * l15 + 1) * 16 + eo8);
    av.u = *(const uint4*)(VsB + l15 * 32 + quad * 8);
    f32x4 ce0 = __builtin_amdgcn_mfma_f32_16x16x32_bf16(ae.b, q20.b, zero4, 0, 0, 0);
    f32x4 co0 = __builtin_amdgcn_mfma_f32_16x16x32_bf16(ao.b, q20.b, zero4, 0, 0, 0);
    f32x4 ce1 = __builtin_amdgcn_mfma_f32_16x16x32_bf16(ae.b, q21.b, zero4, 0, 0, 0);
    f32x4 co1 = __builtin_amdgcn_mfma_f32_16x16x32_bf16(ao.b, q21.b, zero4, 0, 0, 0);
    float pe0[4], po0[4], pe1[4], po1[4];
#pragma unroll
    for (int r = 0; r < 4; ++r) {
      bool ke = (xq + r <= 10), ko = (xq + r <= 9);  // keep keys < 21
      pe0[r] = ke ? __builtin_amdgcn_exp2f(ce0[r]) : 0.f;
      po0[r] = ko ? __builtin_amdgcn_exp2f(co0[r]) : 0.f;
      pe1[r] = ke ? __builtin_amdgcn_exp2f(ce1[r]) : 0.f;
      po1[r] = ko ? __builtin_amdgcn_exp2f(co1[r]) : 0.f;
    }
    t0 = ((pe0[0] + po0[0]) + (pe0[1] + po0[1])) +
         ((pe0[2] + po0[2]) + (pe0[3] + po0[3]));
    t1 = ((pe1[0] + po1[0]) + (pe1[1] + po1[1])) +
         ((pe1[2] + po1[2]) + (pe1[3] + po1[3]));
    U4B pk0, pk1;
    pk0.u.x = pkperm(pe0[0], po0[0]); pk0.u.y = pkperm(pe0[1], po0[1]);
    pk0.u.z = pkperm(pe0[2], po0[2]); pk0.u.w = pkperm(pe0[3], po0[3]);
    pk1.u.x = pkperm(pe1[0], po1[0]); pk1.u.y = pkperm(pe1[1], po1[1]);
    pk1.u.z = pkperm(pe1[2], po1[2]); pk1.u.w = pkperm(pe1[3], po1[3]);
    s0 = __builtin_amdgcn_mfma_f32_16x16x32_bf16(av.b, pk0.b, s0, 0, 0, 0);
    s1 = __builtin_amdgcn_mfma_f32_16x16x32_bf16(av.b, pk1.b, s1, 0, 0, 0);
  }

  // ---- reduce + epilogue (two query fragments) ----
  ls0 += __shfl_xor(ls0, 16, 64); ls0 += __shfl_xor(ls0, 32, 64);
  ls1 += __shfl_xor(ls1, 16, 64); ls1 += __shfl_xor(ls1, 32, 64);
  t0 += __shfl_xor(t0, 16, 64);   t0 += __shfl_xor(t0, 32, 64);
  t1 += __shfl_xor(t1, 16, 64);   t1 += __shfl_xor(t1, 32, 64);
  {
    int n = qw0 + l15;
    float inv1 = __builtin_amdgcn_rcpf(ls0);
    float inv2 = __builtin_amdgcn_rcpf(t0);
    float v0 = o0[0] * inv1, v1 = o0[1] * inv1;
    float v2 = o0[2] * inv1, v3 = o0[3] * inv1;
    if (n >= NST) {
      v0 += s0[0] * inv2; v1 += s0[1] * inv2;
      v2 += s0[2] * inv2; v3 += s0[3] * inv2;
    }
    uint2 w2 = make_uint2(pkbf(v0, v1), pkbf(v2, v3));
    *(uint2*)(heads + ((size_t)b * 1024 + n) * 128 + h * 16 + xq) = w2;
  }
  {
    int n = qw0 + 16 + l15;
    float inv1 = __builtin_amdgcn_rcpf(ls1);
    float inv2 = __builtin_amdgcn_rcpf(t1);
    float v0 = o1[0] * inv1, v1 = o1[1] * inv1;
    float v2 = o1[2] * inv1, v3 = o1[3] * inv1;
    if (n >= NST) {
      v0 += s1[0] * inv2; v1 += s1[1] * inv2;
      v2 += s1[2] * inv2; v3 += s1[3] * inv2;
    }
    uint2 w2 = make_uint2(pkbf(v0, v1), pkbf(v2, v3));
    *(uint2*)(heads + ((size_t)b * 1024 + n) * 128 + h * 16 + xq) = w2;
  }
}

// =====================================================================
extern "C" void kernel_launch(void* const* d_in, const int* in_sizes, int n_in,
                              void* d_out, int out_size, void* d_ws,
                              size_t ws_size, hipStream_t stream) {
  (void)in_sizes; (void)n_in; (void)out_size; (void)ws_size;
  const float* q     = (const float*)d_in[0];
  const float* hx    = (const float*)d_in[1];
  const float* W_qts = (const float*)d_in[2];  // W_query_custom   -> Q_ts
  const float* W_qtt = (const float*)d_in[3];  // W_query_custom_1 -> Q_tt
  const float* W_kc  = (const float*)d_in[4];
  const float* W_vc  = (const float*)d_in[5];
  const float* W_qst = (const float*)d_in[6];  // W_query_charge_1 -> Q_st
  const float* W_ks  = (const float*)d_in[7];
  const float* W_vs  = (const float*)d_in[8];
  const float* W_out = (const float*)d_in[9];

  char* ws = (char*)d_ws;
  u16* qhbf  = (u16*)(ws + 0);          // q:8MB + hx:8MB (bf16 casts)
  u16* heads = (u16*)(ws + 0);          // reuse qbf slot (dead after proj4)
  u16* hbf   = (u16*)(ws + 8388608);
  u16* Qm    = (u16*)(ws + 16777216);   // [h][b][1024][16]
  u16* Qts   = (u16*)(ws + 25165824);
  u16* Kc    = (u16*)(ws + 33554432);   // [h][b][1024][16]
  u16* Vc    = (u16*)(ws + 41943040);   // [h][b][16][1024] (transposed)
  u16* Ks    = (u16*)(ws + 50331648);   // [h][b][32][16]
  u16* Vs    = (u16*)(ws + 50593792);   // [h][b][16][32]
  u16* WtAll = (u16*)(ws + 50855936);   // 5 x 128x128 bf16

  hipLaunchKernelGGL(prep, dim3(4648), dim3(256), 0, stream,
                     q, hx, W_qtt, W_qts, W_kc, W_vc, W_out, W_qst, W_ks, W_vs,
                     qhbf, WtAll, Qm, Ks, Vs);
  hipLaunchKernelGGL(proj4, dim3(2048), dim3(256), 0, stream,
                     qhbf, hbf, WtAll, Qm, Qts, Kc, Vc);
  hipLaunchKernelGGL(attn_main, dim3(2048), dim3(256), 0, stream,
                     Qm, Qts, Kc, Vc, Ks, Vs, heads);
  hipLaunchKernelGGL(outproj, dim3(512), dim3(256), 0, stream,
                     heads, WtAll, (float*)d_out);
}